// Round 13
// baseline (3308.935 us; speedup 1.0000x reference)
//
#include <hip/hip_runtime.h>
#include <stdint.h>

// ---------- types ----------
typedef short short8v __attribute__((ext_vector_type(8)));
typedef float f32x4  __attribute__((ext_vector_type(4)));
typedef unsigned int u32x4 __attribute__((ext_vector_type(4)));
typedef unsigned long long u64;

__device__ inline uint16_t f2bf(float f){
  uint32_t u = __float_as_uint(f);
  uint32_t r = (u + 0x7fffu + ((u >> 16) & 1u)) >> 16;
  return (uint16_t)r;
}
__device__ inline float bf2f(uint16_t h){
  return __uint_as_float(((uint32_t)h) << 16);
}

// ---------- f32 -> bf16 conversion (vectorized) ----------
__global__ void cvt_f32_bf16(const float* __restrict__ src, uint16_t* __restrict__ dst, int n4){
  int i = blockIdx.x * blockDim.x + threadIdx.x;
  int stride = gridDim.x * blockDim.x;
  for (; i < n4; i += stride){
    float4 v = ((const float4*)src)[i];
    uint64_t p = (uint64_t)f2bf(v.x)
               | ((uint64_t)f2bf(v.y) << 16)
               | ((uint64_t)f2bf(v.z) << 32)
               | ((uint64_t)f2bf(v.w) << 48);
    ((uint64_t*)dst)[i] = p;
  }
}

// ---------- bf16 GEMM: C[m,n] = sum_k A[m,k] * Bw[n,k] + bias[n]  (C bf16) ----------
#define GL2LDS(g, l) __builtin_amdgcn_global_load_lds((const __attribute__((address_space(1))) unsigned int*)(g), (__attribute__((address_space(3))) unsigned int*)(l), 16, 0, 0)

__global__ __launch_bounds__(256) void gemm_bt_bias(
    const uint16_t* __restrict__ A, const uint16_t* __restrict__ Bw,
    const float* __restrict__ bias, uint16_t* __restrict__ C,
    int M, int N, int K)
{
  __shared__ uint16_t As[128 * 64];
  __shared__ uint16_t Bs[128 * 64];
  const int tid  = threadIdx.x;
  const int lane = tid & 63, wid = tid >> 6;
  const int n0 = blockIdx.x * 128, m0 = blockIdx.y * 128;
  const int wrow = (wid & 1) * 64, wcol = (wid >> 1) * 64;
  const int l15 = lane & 15, l4 = lane >> 4;
  const int srow = lane >> 3, scol = (lane & 7) * 8;
  const size_t Ks = (size_t)K;

  f32x4 acc[4][4] = {};

  for (int kt = 0; kt < K; kt += 64){
    __syncthreads();
    const uint16_t* gA = A  + (size_t)m0 * Ks + kt;
    const uint16_t* gB = Bw + (size_t)n0 * Ks + kt;
    #pragma unroll
    for (int i = 0; i < 4; ++i){
      int rb = wid * 32 + i * 8;
      GL2LDS(gA + (size_t)(rb + srow) * Ks + scol, &As[rb * 64]);
      GL2LDS(gB + (size_t)(rb + srow) * Ks + scol, &Bs[rb * 64]);
    }
    __syncthreads();
    #pragma unroll
    for (int kk = 0; kk < 2; ++kk){
      short8v a[4], b[4];
      int koff = kk * 32 + l4 * 8;
      #pragma unroll
      for (int mt = 0; mt < 4; ++mt) a[mt] = *(const short8v*)&As[(wrow + mt*16 + l15) * 64 + koff];
      #pragma unroll
      for (int nt = 0; nt < 4; ++nt) b[nt] = *(const short8v*)&Bs[(wcol + nt*16 + l15) * 64 + koff];
      #pragma unroll
      for (int mt = 0; mt < 4; ++mt)
        #pragma unroll
        for (int nt = 0; nt < 4; ++nt)
          acc[mt][nt] = __builtin_amdgcn_mfma_f32_16x16x32_bf16(a[mt], b[nt], acc[mt][nt], 0, 0, 0);
    }
  }
  #pragma unroll
  for (int mt = 0; mt < 4; ++mt)
    #pragma unroll
    for (int nt = 0; nt < 4; ++nt){
      int col = n0 + wcol + nt * 16 + l15;
      float bv = bias[col];
      int rbase = m0 + wrow + mt * 16 + l4 * 4;
      #pragma unroll
      for (int j = 0; j < 4; ++j)
        C[(size_t)(rbase + j) * (size_t)N + col] = f2bf(acc[mt][nt][j] + bv);
    }
}

// LDS reduce index, stride 72 f32 (=18 4-bank granules, 18 mod 8 = 2):
// f32x4 writes land exactly 8 lanes per granule (conflict-free); scalar reads
// 2-way aliased (free). Verified r10: conflicts 8.2e7 -> 1.26e7.
__device__ inline int ridx(int w, int c, int m){
  return (w * 48 + c) * 72 + (m ^ ((c & 7) << 2));
}

// 16B h load: PLAIN CACHED (L1+L2). Freshness by the 32-deep ring + one
// acquire fence (L1+L2 inv) per 32-step epoch per wave: every slot line is
// read once per epoch per block, after that wave's fence; the slot's next
// write (write-through to MALL) lands before any post-fence read of it.
#define HLOAD(dst, addr) \
  asm volatile("global_load_dwordx4 %0, %1, off" : "=v"(dst) : "v"(addr) : "memory")
// plain cached 8B load (xp), participates in the counted window
#define XPLOAD(dst, addr) \
  asm volatile("global_load_dwordx2 %0, %1, off" : "=v"(dst) : "v"(addr) : "memory")
// coalesced MALL write-through stores (proven r5/r10)
#define HSTORE8(addr, val) \
  asm volatile("global_store_dwordx2 %0, %1, off sc0 sc1" :: "v"(addr), "v"(val) : "memory")
#define OSTORE8(addr, val) \
  asm volatile("global_store_dwordx2 %0, %1, off nt" :: "v"(addr), "v"(val) : "memory")
#define OSTORE16(addr, val) \
  asm volatile("global_store_dwordx4 %0, %1, off nt" :: "v"(addr), "v"(val) : "memory")
#define WAITVM(n) do { asm volatile("s_waitcnt vmcnt(" #n ")" ::: "memory"); \
                       __builtin_amdgcn_sched_barrier(0); } while (0)

// ---------- persistent bidirectional GRU layer ----------
// grid = 128 blocks x 256 threads: dir = blk>>6, columns c0 = (blk&63)*16 of H.
// h state: 32-slot ring of compact per-block 2KB chunks
// [32 slot][2 dir][64 blk][64 rows][16 cols]. Producers write through to MALL
// (sc0sc1, ack, flag — r10-proven). Consumers read PLAIN CACHED; wave wid
// consumes chunks wid*16..wid*16+15, so it polls only those 16 producer flags
// and proceeds immediately (no post-poll block barrier).
__global__ __launch_bounds__(256, 1) void gru_layer(
    const uint16_t* __restrict__ xp,   // (T,B,3H) bf16 (bias already added)
    const uint16_t* __restrict__ U,    // (3H, H) bf16, rows: Ur | Uz | Un
    const float* __restrict__ bn,      // (H)
    u64* __restrict__ hbuf,            // 32 x [2 dir][64 blk][256 u64] = 8 MB
    uint16_t* __restrict__ out_bf,     // (T,B,2H) bf16 or null
    float* __restrict__ out_f32,       // (T,B,2H) f32 or null
    float* __restrict__ hid,           // 2 slots of (64,1024) f32: fwd then bwd
    unsigned* __restrict__ flags)      // [2 dir][64] packed u32
{
  __shared__ float red[4 * 48 * 72];
  const int tid  = threadIdx.x;
  const int lane = tid & 63, wid = tid >> 6;
  const int dir  = blockIdx.x >> 6;
  const int blkc = blockIdx.x & 63;
  const int c0   = blkc * 16;
  const int l15 = lane & 15, l4 = lane >> 4;
  unsigned* myflags = flags + dir * 64;

  // register-resident B fragments (U weights), reused for all 256 steps
  short8v bfr[3][8];
  #pragma unroll
  for (int g = 0; g < 3; ++g)
    #pragma unroll
    for (int k32 = 0; k32 < 8; ++k32){
      int row = g * 1024 + c0 + l15;
      int k   = wid * 256 + k32 * 32 + l4 * 8;
      bfr[g][k32] = *(const short8v*)&U[(size_t)row * 1024 + k];
    }

  // gate mapping: thread -> (row gm, 4 consecutive cols gc..gc+3)
  const int g4 = tid & 3, gm = tid >> 2;
  const int gc = c0 + g4 * 4;
  float hold[4] = {0.f, 0.f, 0.f, 0.f};
  float bnv[4];
  #pragma unroll
  for (int j = 0; j < 4; ++j) bnv[j] = bn[gc + j];

  // consumer h geometry (compact chunks): global col = wid*256 + c*32 + l4*8 + [0..7]
  // chunk = col/16 ; byte addr = chunk*2048 + row*32 + (col%16)*2
  const size_t hoff = (size_t)(wid * 16 + (l4 >> 1)) * 2048 + (size_t)(l4 & 1) * 16 + (size_t)l15 * 32;

  // pre-loop fence: clear cross-dispatch / cross-layer cached hbuf residue
  __builtin_amdgcn_fence(__ATOMIC_ACQUIRE, "agent");

  for (int s = 0; s < 256; ++s){
    const int t = dir ? (255 - s) : s;
    const size_t xb2 = ((size_t)t * 64 + gm) * 3072 + gc;

    f32x4 acc[3][4] = {};
    u64 pxr, pxz, pxn;
    if (s > 0){
      // ---- per-wave poll: only the 16 producer blocks of MY chunks ----
      {
        const unsigned tgt = (unsigned)s;
        const unsigned* fp = myflags + wid * 16 + (lane & 15);
        int spins = 0;
        for (;;){
          unsigned v;
          asm volatile("global_load_dword %0, %1, off sc0 sc1" : "=v"(v) : "v"(fp) : "memory");
          asm volatile("s_waitcnt vmcnt(0)" ::: "memory");
          if (__all((int)(v >= tgt))) break;
          __builtin_amdgcn_s_sleep(1);
          if (((++spins) & 1023) == 0)
            __builtin_amdgcn_fence(__ATOMIC_ACQUIRE, "agent");   // deadlock safety valve
        }
      }

      // epoch fence (per wave, before its own loads): slot re-read after >=32
      // steps; invalidates any L1/L2 copy cached in the previous epoch.
      if ((s & 31) == 0)
        __builtin_amdgcn_fence(__ATOMIC_ACQUIRE, "agent");

      const char* hbase = (const char*)(hbuf + (size_t)((s & 31) * 2 + dir) * (64 * 256));

      // ---- K-window: 3 chunks ahead; xp folded in at kk==4 (same-iter use) ----
      short8v hc[8][4];
      #pragma unroll
      for (int c = 0; c < 3; ++c)
        #pragma unroll
        for (int mt = 0; mt < 4; ++mt)
          HLOAD(hc[c][mt], hbase + hoff + (size_t)c * 4096 + (size_t)mt * 512);

      #pragma unroll
      for (int kk = 0; kk < 8; ++kk){
        if (kk < 5){
          #pragma unroll
          for (int mt = 0; mt < 4; ++mt)
            HLOAD(hc[kk + 3][mt], hbase + hoff + (size_t)(kk + 3) * 4096 + (size_t)mt * 512);
        }
        if (kk == 4){   // xp loads issued after ALL h loads (in-order retire)
          XPLOAD(pxr, &xp[xb2]);
          XPLOAD(pxz, &xp[xb2 + 1024]);
          XPLOAD(pxn, &xp[xb2 + 2048]);
        }
        if      (kk <  4) WAITVM(12);
        else if (kk == 4) WAITVM(15);
        else if (kk == 5) WAITVM(11);
        else if (kk == 6) WAITVM(7);
        else              WAITVM(3);
        #pragma unroll
        for (int g = 0; g < 3; ++g)
          #pragma unroll
          for (int mt = 0; mt < 4; ++mt)
            acc[g][mt] = __builtin_amdgcn_mfma_f32_16x16x32_bf16(hc[kk][mt], bfr[g][kk], acc[g][mt], 0, 0, 0);
      }
    } else {
      pxr = *(const u64*)&xp[xb2];
      pxz = *(const u64*)&xp[xb2 + 1024];
      pxn = *(const u64*)&xp[xb2 + 2048];
    }

    // write partial sums to LDS (stride-72 swizzled, conflict-free writes)
    #pragma unroll
    for (int g = 0; g < 3; ++g)
      #pragma unroll
      for (int mt = 0; mt < 4; ++mt)
        *(f32x4*)&red[ridx(wid, g * 16 + l15, mt * 16 + l4 * 4)] = acc[g][mt];
    __syncthreads();                       // sync1: all partials ready

    // reduce over 4 waves; thread -> (row gm, cols g4*4..+3)
    float ra[4] = {}, za[4] = {}, na[4] = {};
    #pragma unroll
    for (int w = 0; w < 4; ++w)
      #pragma unroll
      for (int j = 0; j < 4; ++j){
        ra[j] += red[ridx(w,      g4 * 4 + j, gm)];
        za[j] += red[ridx(w, 16 + g4 * 4 + j, gm)];
        na[j] += red[ridx(w, 32 + g4 * 4 + j, gm)];
      }

    WAITVM(0);                             // xp in registers (queue empty)
    u64 hv = 0;
    float hn[4];
    #pragma unroll
    for (int j = 0; j < 4; ++j){
      float xr = bf2f((uint16_t)(pxr >> (16 * j)));
      float xz = bf2f((uint16_t)(pxz >> (16 * j)));
      float xn = bf2f((uint16_t)(pxn >> (16 * j)));
      float r = 1.f / (1.f + __expf(-(xr + ra[j])));
      float z = 1.f / (1.f + __expf(-(xz + za[j])));
      float n = tanhf(xn + r * (na[j] + bnv[j]));
      hn[j] = (1.f - z) * n + z * hold[j];
      hold[j] = hn[j];
      hv |= ((u64)f2bf(hn[j])) << (16 * j);
    }

    if (s < 255){
      // compact h store into ring slot (s+1)&31: wave-contiguous 512B,
      // coalesced write-through to MALL (proven)
      u64* hw = hbuf + ((size_t)((((s + 1) & 31) * 2 + dir) * 64 + blkc)) * 256;
      HSTORE8(&hw[gm * 4 + g4], hv);
      WAITVM(0);                           // h committed (this wave)
      __syncthreads();                     // commit-sync: all waves' h + red reads done
      if (tid == 0)
        __hip_atomic_store(&myflags[blkc], (unsigned)(s + 1), __ATOMIC_RELAXED, __HIP_MEMORY_SCOPE_AGENT);
      __builtin_amdgcn_sched_barrier(0);
    }

    // out store AFTER flag (1 counted txn/thread; drains in next poll)
    {
      size_t obase = ((size_t)t * 64 + gm) * 2048 + (size_t)dir * 1024 + gc;
      if (out_bf) OSTORE8(&out_bf[obase], hv);
      else {
        f32x4 ov = { hn[0], hn[1], hn[2], hn[3] };
        OSTORE16(&out_f32[obase], ov);
      }
      if (s == 255){
        f32x4 hvv = { hn[0], hn[1], hn[2], hn[3] };
        *(f32x4*)&hid[((size_t)dir * 64 + gm) * 1024 + gc] = hvv;
      }
    }
  }
}

// ---------- host ----------
extern "C" void kernel_launch(void* const* d_in, const int* in_sizes, int n_in,
                              void* d_out, int out_size, void* d_ws, size_t ws_size,
                              hipStream_t stream) {
  const float* x   = (const float*)d_in[0];
  const float* W0  = (const float*)d_in[1];
  const float* b0  = (const float*)d_in[2];
  const float* Ur0 = (const float*)d_in[3];
  const float* Uz0 = (const float*)d_in[4];
  const float* Un0 = (const float*)d_in[5];
  const float* bn0 = (const float*)d_in[6];
  const float* W1  = (const float*)d_in[7];
  const float* b1  = (const float*)d_in[8];
  const float* Ur1 = (const float*)d_in[9];
  const float* Uz1 = (const float*)d_in[10];
  const float* Un1 = (const float*)d_in[11];
  const float* bn1 = (const float*)d_in[12];
  float* out = (float*)d_out;

  char* base = (char*)d_ws;
  unsigned* ctr0 = (unsigned*)base;                  // layer0 flags (2 dirs * 256B)
  unsigned* ctr1 = (unsigned*)(base + 4096);         // layer1 flags
  uint16_t* xb    = (uint16_t*)(base + 8192);
  uint16_t* w0b   = xb    + (size_t)16384 * 1024;
  uint16_t* u0b   = w0b   + (size_t)3072 * 1024;
  uint16_t* w1b   = u0b   + (size_t)3072 * 1024;
  uint16_t* u1b   = w1b   + (size_t)3072 * 2048;
  uint16_t* xp    = u1b   + (size_t)3072 * 1024;
  uint16_t* out0b = xp    + (size_t)16384 * 3072;
  u64*      hbuf  = (u64*)(out0b + (size_t)16384 * 2048);   // 32-slot ring, 8 MB

  hipMemsetAsync(d_ws, 0, 8192, stream);

  auto cvt = [&](const float* s, uint16_t* d, size_t n){
    int n4 = (int)(n / 4);
    int grid = (n4 + 255) / 256; if (grid > 2048) grid = 2048;
    hipLaunchKernelGGL(cvt_f32_bf16, dim3(grid), dim3(256), 0, stream, s, d, n4);
  };
  cvt(x,   xb,  (size_t)16384 * 1024);
  cvt(W0,  w0b, (size_t)3072 * 1024);
  cvt(Ur0, u0b + 0 * (size_t)1024 * 1024, (size_t)1024 * 1024);
  cvt(Uz0, u0b + 1 * (size_t)1024 * 1024, (size_t)1024 * 1024);
  cvt(Un0, u0b + 2 * (size_t)1024 * 1024, (size_t)1024 * 1024);
  cvt(W1,  w1b, (size_t)3072 * 2048);
  cvt(Ur1, u1b + 0 * (size_t)1024 * 1024, (size_t)1024 * 1024);
  cvt(Uz1, u1b + 1 * (size_t)1024 * 1024, (size_t)1024 * 1024);
  cvt(Un1, u1b + 2 * (size_t)1024 * 1024, (size_t)1024 * 1024);

  // layer 0: xp0 = x @ W0^T + b0
  hipLaunchKernelGGL(gemm_bt_bias, dim3(24, 128), dim3(256), 0, stream,
                     xb, w0b, b0, xp, 16384, 3072, 1024);
  // layer 0 recurrence -> out0b (bf16), hidden slots 0,1
  hipLaunchKernelGGL(gru_layer, dim3(128), dim3(256), 0, stream,
                     xp, u0b, bn0, hbuf,
                     out0b, (float*)nullptr,
                     out + (size_t)33554432, ctr0);
  // layer 1: xp1 = out0 @ W1^T + b1
  hipLaunchKernelGGL(gemm_bt_bias, dim3(24, 128), dim3(256), 0, stream,
                     out0b, w1b, b1, xp, 16384, 3072, 2048);
  // layer 1 recurrence -> d_out (f32), hidden slots 2,3
  hipLaunchKernelGGL(gru_layer, dim3(128), dim3(256), 0, stream,
                     xp, u1b, bn1, hbuf,
                     (uint16_t*)nullptr, out,
                     out + (size_t)33554432 + (size_t)2 * 64 * 1024, ctr1);
}

// Round 15
// 2993.428 us; speedup vs baseline: 1.1054x; 1.1054x over previous
//
#include <hip/hip_runtime.h>
#include <stdint.h>

// ---------- types ----------
typedef short short8v __attribute__((ext_vector_type(8)));
typedef float f32x4  __attribute__((ext_vector_type(4)));
typedef float f32x2  __attribute__((ext_vector_type(2)));
typedef unsigned int u32x4 __attribute__((ext_vector_type(4)));
typedef unsigned long long u64;

__device__ inline uint16_t f2bf(float f){
  uint32_t u = __float_as_uint(f);
  uint32_t r = (u + 0x7fffu + ((u >> 16) & 1u)) >> 16;
  return (uint16_t)r;
}
__device__ inline float bf2f(uint16_t h){
  return __uint_as_float(((uint32_t)h) << 16);
}

// ---------- f32 -> bf16 conversion (vectorized) ----------
__global__ void cvt_f32_bf16(const float* __restrict__ src, uint16_t* __restrict__ dst, int n4){
  int i = blockIdx.x * blockDim.x + threadIdx.x;
  int stride = gridDim.x * blockDim.x;
  for (; i < n4; i += stride){
    float4 v = ((const float4*)src)[i];
    uint64_t p = (uint64_t)f2bf(v.x)
               | ((uint64_t)f2bf(v.y) << 16)
               | ((uint64_t)f2bf(v.z) << 32)
               | ((uint64_t)f2bf(v.w) << 48);
    ((uint64_t*)dst)[i] = p;
  }
}

// ---------- bf16 GEMM: C[m,n] = sum_k A[m,k] * Bw[n,k] + bias[n]  (C bf16) ----------
#define GL2LDS(g, l) __builtin_amdgcn_global_load_lds((const __attribute__((address_space(1))) unsigned int*)(g), (__attribute__((address_space(3))) unsigned int*)(l), 16, 0, 0)

__global__ __launch_bounds__(256) void gemm_bt_bias(
    const uint16_t* __restrict__ A, const uint16_t* __restrict__ Bw,
    const float* __restrict__ bias, uint16_t* __restrict__ C,
    int M, int N, int K)
{
  __shared__ uint16_t As[128 * 64];
  __shared__ uint16_t Bs[128 * 64];
  const int tid  = threadIdx.x;
  const int lane = tid & 63, wid = tid >> 6;
  const int n0 = blockIdx.x * 128, m0 = blockIdx.y * 128;
  const int wrow = (wid & 1) * 64, wcol = (wid >> 1) * 64;
  const int l15 = lane & 15, l4 = lane >> 4;
  const int srow = lane >> 3, scol = (lane & 7) * 8;
  const size_t Ks = (size_t)K;

  f32x4 acc[4][4] = {};

  for (int kt = 0; kt < K; kt += 64){
    __syncthreads();
    const uint16_t* gA = A  + (size_t)m0 * Ks + kt;
    const uint16_t* gB = Bw + (size_t)n0 * Ks + kt;
    #pragma unroll
    for (int i = 0; i < 4; ++i){
      int rb = wid * 32 + i * 8;
      GL2LDS(gA + (size_t)(rb + srow) * Ks + scol, &As[rb * 64]);
      GL2LDS(gB + (size_t)(rb + srow) * Ks + scol, &Bs[rb * 64]);
    }
    __syncthreads();
    #pragma unroll
    for (int kk = 0; kk < 2; ++kk){
      short8v a[4], b[4];
      int koff = kk * 32 + l4 * 8;
      #pragma unroll
      for (int mt = 0; mt < 4; ++mt) a[mt] = *(const short8v*)&As[(wrow + mt*16 + l15) * 64 + koff];
      #pragma unroll
      for (int nt = 0; nt < 4; ++nt) b[nt] = *(const short8v*)&Bs[(wcol + nt*16 + l15) * 64 + koff];
      #pragma unroll
      for (int mt = 0; mt < 4; ++mt)
        #pragma unroll
        for (int nt = 0; nt < 4; ++nt)
          acc[mt][nt] = __builtin_amdgcn_mfma_f32_16x16x32_bf16(a[mt], b[nt], acc[mt][nt], 0, 0, 0);
    }
  }
  #pragma unroll
  for (int mt = 0; mt < 4; ++mt)
    #pragma unroll
    for (int nt = 0; nt < 4; ++nt){
      int col = n0 + wcol + nt * 16 + l15;
      float bv = bias[col];
      int rbase = m0 + wrow + mt * 16 + l4 * 4;
      #pragma unroll
      for (int j = 0; j < 4; ++j)
        C[(size_t)(rbase + j) * (size_t)N + col] = f2bf(acc[mt][nt][j] + bv);
    }
}

// LDS reduce index, stride 72 f32 (verified r10: conflict-free f32x4 writes)
__device__ inline int ridx(int w, int c, int m){
  return (w * 48 + c) * 72 + (m ^ ((c & 7) << 2));
}

// 16B MALL-direct load (bypass L1+L2) — proven r4/r10
#define HLOAD(dst, addr) \
  asm volatile("global_load_dwordx4 %0, %1, off sc0 sc1" : "=v"(dst) : "v"(addr) : "memory")
// plain cached 4B load (xp), participates in the counted window
#define XPLOAD4(dst, addr) \
  asm volatile("global_load_dword %0, %1, off" : "=v"(dst) : "v"(addr) : "memory")
// coalesced MALL write-through 4B store (h)
#define HSTORE4(addr, val) \
  asm volatile("global_store_dword %0, %1, off sc0 sc1" :: "v"(addr), "v"(val) : "memory")
#define OSTORE4(addr, val) \
  asm volatile("global_store_dword %0, %1, off nt" :: "v"(addr), "v"(val) : "memory")
#define OSTORE8(addr, val) \
  asm volatile("global_store_dwordx2 %0, %1, off nt" :: "v"(addr), "v"(val) : "memory")
#define WAITVM(n) do { asm volatile("s_waitcnt vmcnt(" #n ")" ::: "memory"); \
                       __builtin_amdgcn_sched_barrier(0); } while (0)

// ---------- persistent bidirectional GRU layer, 2-D decomposition ----------
// Batch rows are independent across the recurrence -> split batch into 2
// groups of 32 rows. grid = 256 blocks x 256 threads:
//   dir = bid>>7, grp = (bid>>6)&1, colblk cb = bid&63 (16 h-cols each).
// Each block computes h[32 rows][16 cols]; it needs h_old[its 32 rows][1024]
// = 64 KB/step gathered from the 64 blocks of ITS group only (vs 128 KB in
// the 1-D design). Sync is per-group (64 flags). Protocol identical to r10:
// sc0sc1 write-through h chunks + ack + packed-flag poll; counted-vmcnt
// K-window with xp folded in; stride-72 LDS reduce.
__global__ __launch_bounds__(256, 1) void gru_layer(
    const uint16_t* __restrict__ xp,   // (T,B,3H) bf16 (bias already added)
    const uint16_t* __restrict__ U,    // (3H, H) bf16, rows: Ur | Uz | Un
    const float* __restrict__ bn,      // (H)
    u64* __restrict__ hbuf,            // [2 par][4 group][64 blk][1KB chunk]
    uint16_t* __restrict__ out_bf,     // (T,B,2H) bf16 or null
    float* __restrict__ out_f32,       // (T,B,2H) f32 or null
    float* __restrict__ hid,           // 2 slots of (64,1024) f32: fwd then bwd
    unsigned* __restrict__ flags)      // [4 group][64] packed u32
{
  __shared__ float red[4 * 48 * 72];
  const int tid  = threadIdx.x;
  const int lane = tid & 63, wid = tid >> 6;
  const int bid  = blockIdx.x;
  const int dir  = bid >> 7;
  const int g4   = bid >> 6;            // group id 0..3 (dir*2+grp)
  const int grp  = g4 & 1;
  const int cb   = bid & 63;
  const int c0   = cb * 16;
  const int brow0 = grp * 32;           // global batch-row base
  const int l15 = lane & 15, l4 = lane >> 4;
  unsigned* myflags = flags + g4 * 64;

  // register-resident B fragments (U weights), reused for all 256 steps
  short8v bfr[3][8];
  #pragma unroll
  for (int g = 0; g < 3; ++g)
    #pragma unroll
    for (int k32 = 0; k32 < 8; ++k32){
      int row = g * 1024 + c0 + l15;
      int k   = wid * 256 + k32 * 32 + l4 * 8;
      bfr[g][k32] = *(const short8v*)&U[(size_t)row * 1024 + k];
    }

  // gate mapping: thread -> (row gm 0..31, col pair cp, cp+1)
  const int gm = tid >> 3;
  const int cp = (tid & 7) * 2;
  float hold[2] = {0.f, 0.f};
  float bnv[2] = { bn[c0 + cp], bn[c0 + cp + 1] };

  // consumer h geometry: chunk = wid*16 + k32*2 + (l4>>1) (1KB chunks of
  // [32 rows][16 cols]); byte = chunk*1024 + (mt*16+l15)*32 + (l4&1)*16
  const size_t hoff = (size_t)(wid * 16 + (l4 >> 1)) * 1024 + (size_t)(l4 & 1) * 16 + (size_t)l15 * 32;

  for (int s = 0; s < 256; ++s){
    const int par = s & 1;
    const int t = dir ? (255 - s) : s;
    const size_t xb2 = ((size_t)t * 64 + brow0 + gm) * 3072 + c0 + cp;

    f32x4 acc[3][2] = {};
    unsigned pxr, pxz, pxn;
    if (s > 0){
      // ---- wave0 polls the 64 packed flags of MY group (dwordx4) ----
      if (wid == 0){
        const unsigned tgt = (unsigned)s;
        const unsigned* fp = myflags + (lane & 15) * 4;
        int spins = 0;
        for (;;){
          u32x4 fv;
          asm volatile("global_load_dwordx4 %0, %1, off sc0 sc1" : "=v"(fv) : "v"(fp) : "memory");
          asm volatile("s_waitcnt vmcnt(0)" ::: "memory");
          if (__all((int)(fv.x >= tgt && fv.y >= tgt && fv.z >= tgt && fv.w >= tgt))) break;
          __builtin_amdgcn_s_sleep(1);
          if (((++spins) & 1023) == 0)
            __builtin_amdgcn_fence(__ATOMIC_ACQUIRE, "agent");   // deadlock safety valve
        }
      }
      __syncthreads();

      const char* hgbase = (const char*)hbuf + ((size_t)(par * 4 + g4) * 64) * 1024;

      // ---- K-window: 3 k32-chunks ahead (2 loads each); xp at kk==4 ----
      short8v hc[8][2];
      #pragma unroll
      for (int c = 0; c < 3; ++c)
        #pragma unroll
        for (int mt = 0; mt < 2; ++mt)
          HLOAD(hc[c][mt], hgbase + hoff + (size_t)c * 2048 + (size_t)mt * 512);

      #pragma unroll
      for (int kk = 0; kk < 8; ++kk){
        if (kk < 5){
          #pragma unroll
          for (int mt = 0; mt < 2; ++mt)
            HLOAD(hc[kk + 3][mt], hgbase + hoff + (size_t)(kk + 3) * 2048 + (size_t)mt * 512);
        }
        if (kk == 4){   // xp loads issued after ALL h loads (in-order retire)
          XPLOAD4(pxr, &xp[xb2]);
          XPLOAD4(pxz, &xp[xb2 + 1024]);
          XPLOAD4(pxn, &xp[xb2 + 2048]);
        }
        if      (kk <  4) WAITVM(6);
        else if (kk == 4) WAITVM(9);
        else if (kk == 5) WAITVM(7);
        else if (kk == 6) WAITVM(5);
        else              WAITVM(3);
        #pragma unroll
        for (int g = 0; g < 3; ++g)
          #pragma unroll
          for (int mt = 0; mt < 2; ++mt)
            acc[g][mt] = __builtin_amdgcn_mfma_f32_16x16x32_bf16(hc[kk][mt], bfr[g][kk], acc[g][mt], 0, 0, 0);
      }
    } else {
      pxr = *(const unsigned*)&xp[xb2];
      pxz = *(const unsigned*)&xp[xb2 + 1024];
      pxn = *(const unsigned*)&xp[xb2 + 2048];
    }

    // write partial sums to LDS (stride-72 swizzled; m<32 fits the slot)
    #pragma unroll
    for (int g = 0; g < 3; ++g)
      #pragma unroll
      for (int mt = 0; mt < 2; ++mt)
        *(f32x4*)&red[ridx(wid, g * 16 + l15, mt * 16 + l4 * 4)] = acc[g][mt];
    __syncthreads();                       // sync1: all partials ready

    // reduce over 4 waves; thread -> (row gm, cols cp, cp+1)
    float ra[2] = {}, za[2] = {}, na[2] = {};
    #pragma unroll
    for (int w = 0; w < 4; ++w)
      #pragma unroll
      for (int j = 0; j < 2; ++j){
        ra[j] += red[ridx(w,      cp + j, gm)];
        za[j] += red[ridx(w, 16 + cp + j, gm)];
        na[j] += red[ridx(w, 32 + cp + j, gm)];
      }

    WAITVM(0);                             // xp in registers (queue empty)
    unsigned hv = 0;
    float hn[2];
    #pragma unroll
    for (int j = 0; j < 2; ++j){
      float xr = bf2f((uint16_t)(pxr >> (16 * j)));
      float xz = bf2f((uint16_t)(pxz >> (16 * j)));
      float xn = bf2f((uint16_t)(pxn >> (16 * j)));
      float r = 1.f / (1.f + __expf(-(xr + ra[j])));
      float z = 1.f / (1.f + __expf(-(xz + za[j])));
      float n = tanhf(xn + r * (na[j] + bnv[j]));
      hn[j] = (1.f - z) * n + z * hold[j];
      hold[j] = hn[j];
      hv |= ((unsigned)f2bf(hn[j])) << (16 * j);
    }

    if (s < 255){
      // own-chunk h store: wave-contiguous 256B, write-through to MALL
      char* hw = (char*)hbuf + ((size_t)((par ^ 1) * 4 + g4) * 64 + cb) * 1024
               + (size_t)gm * 32 + (size_t)cp * 2;
      HSTORE4(hw, hv);
      WAITVM(0);                           // h committed (this wave)
      __syncthreads();                     // commit-sync: all waves' h + red reads done
      if (tid == 0)
        __hip_atomic_store(&myflags[cb], (unsigned)(s + 1), __ATOMIC_RELAXED, __HIP_MEMORY_SCOPE_AGENT);
      __builtin_amdgcn_sched_barrier(0);
    }

    // out store AFTER flag (drains in next poll)
    {
      size_t obase = ((size_t)t * 64 + brow0 + gm) * 2048 + (size_t)dir * 1024 + c0 + cp;
      if (out_bf) OSTORE4(&out_bf[obase], hv);
      else {
        f32x2 ov = { hn[0], hn[1] };
        OSTORE8(&out_f32[obase], ov);
      }
      if (s == 255){
        f32x2 hvv = { hn[0], hn[1] };
        *(f32x2*)&hid[((size_t)dir * 64 + brow0 + gm) * 1024 + c0 + cp] = hvv;
      }
    }
  }
}

// ---------- host ----------
extern "C" void kernel_launch(void* const* d_in, const int* in_sizes, int n_in,
                              void* d_out, int out_size, void* d_ws, size_t ws_size,
                              hipStream_t stream) {
  const float* x   = (const float*)d_in[0];
  const float* W0  = (const float*)d_in[1];
  const float* b0  = (const float*)d_in[2];
  const float* Ur0 = (const float*)d_in[3];
  const float* Uz0 = (const float*)d_in[4];
  const float* Un0 = (const float*)d_in[5];
  const float* bn0 = (const float*)d_in[6];
  const float* W1  = (const float*)d_in[7];
  const float* b1  = (const float*)d_in[8];
  const float* Ur1 = (const float*)d_in[9];
  const float* Uz1 = (const float*)d_in[10];
  const float* Un1 = (const float*)d_in[11];
  const float* bn1 = (const float*)d_in[12];
  float* out = (float*)d_out;

  char* base = (char*)d_ws;
  unsigned* ctr0 = (unsigned*)base;                  // layer0 flags (4 groups * 256B)
  unsigned* ctr1 = (unsigned*)(base + 4096);         // layer1 flags
  uint16_t* xb    = (uint16_t*)(base + 8192);
  uint16_t* w0b   = xb    + (size_t)16384 * 1024;
  uint16_t* u0b   = w0b   + (size_t)3072 * 1024;
  uint16_t* w1b   = u0b   + (size_t)3072 * 1024;
  uint16_t* u1b   = w1b   + (size_t)3072 * 2048;
  uint16_t* xp    = u1b   + (size_t)3072 * 1024;
  uint16_t* out0b = xp    + (size_t)16384 * 3072;
  u64*      hbuf  = (u64*)(out0b + (size_t)16384 * 2048);   // 512 KB chunks

  hipMemsetAsync(d_ws, 0, 8192, stream);

  auto cvt = [&](const float* s, uint16_t* d, size_t n){
    int n4 = (int)(n / 4);
    int grid = (n4 + 255) / 256; if (grid > 2048) grid = 2048;
    hipLaunchKernelGGL(cvt_f32_bf16, dim3(grid), dim3(256), 0, stream, s, d, n4);
  };
  cvt(x,   xb,  (size_t)16384 * 1024);
  cvt(W0,  w0b, (size_t)3072 * 1024);
  cvt(Ur0, u0b + 0 * (size_t)1024 * 1024, (size_t)1024 * 1024);
  cvt(Uz0, u0b + 1 * (size_t)1024 * 1024, (size_t)1024 * 1024);
  cvt(Un0, u0b + 2 * (size_t)1024 * 1024, (size_t)1024 * 1024);
  cvt(W1,  w1b, (size_t)3072 * 2048);
  cvt(Ur1, u1b + 0 * (size_t)1024 * 1024, (size_t)1024 * 1024);
  cvt(Uz1, u1b + 1 * (size_t)1024 * 1024, (size_t)1024 * 1024);
  cvt(Un1, u1b + 2 * (size_t)1024 * 1024, (size_t)1024 * 1024);

  // layer 0: xp0 = x @ W0^T + b0
  hipLaunchKernelGGL(gemm_bt_bias, dim3(24, 128), dim3(256), 0, stream,
                     xb, w0b, b0, xp, 16384, 3072, 1024);
  // layer 0 recurrence -> out0b (bf16), hidden slots 0,1
  hipLaunchKernelGGL(gru_layer, dim3(256), dim3(256), 0, stream,
                     xp, u0b, bn0, hbuf,
                     out0b, (float*)nullptr,
                     out + (size_t)33554432, ctr0);
  // layer 1: xp1 = out0 @ W1^T + b1
  hipLaunchKernelGGL(gemm_bt_bias, dim3(24, 128), dim3(256), 0, stream,
                     out0b, w1b, b1, xp, 16384, 3072, 2048);
  // layer 1 recurrence -> d_out (f32), hidden slots 2,3
  hipLaunchKernelGGL(gru_layer, dim3(256), dim3(256), 0, stream,
                     xp, u1b, bn1, hbuf,
                     (uint16_t*)nullptr, out,
                     out + (size_t)33554432 + (size_t)2 * 64 * 1024, ctr1);
}